// Round 18
// baseline (445.120 us; speedup 1.0000x reference)
//
#include <hip/hip_runtime.h>
#include <hip/hip_bf16.h>
#include <math.h>

#ifndef M_PI
#define M_PI 3.14159265358979323846
#endif

typedef unsigned short u16;
typedef short short8 __attribute__((ext_vector_type(8)));
typedef float f32x4 __attribute__((ext_vector_type(4)));
typedef float f32x2 __attribute__((ext_vector_type(2)));
typedef unsigned int u32x4 __attribute__((ext_vector_type(4)));

#define CIN  256
#define CH   128
#define HW   10000
#define NA   100
#define NR   100

__device__ __forceinline__ float bf2f(u16 v) {
  return __uint_as_float(((unsigned int)v) << 16);
}
__device__ __forceinline__ u16 f2bf(float f) {
  unsigned int u = __float_as_uint(f);
  u += 0x7fffu + ((u >> 16) & 1u);   // round-to-nearest-even
  return (u16)(u >> 16);
}
__device__ __forceinline__ f32x2 bfpair(unsigned int v) {
  f32x2 r;
  r.x = __uint_as_float(v << 16);
  r.y = __uint_as_float(v & 0xffff0000u);
  return r;
}

// ---------------------------------------------------------------------------
// prep+csr merged: blocks 0..99 csr (+ per-wave bin ranges); 100..675 weights.
// wbf1 pre-scaled by BN scale; bias1 = b1*s + be1. (unchanged from R16)
// ---------------------------------------------------------------------------
__global__ void __launch_bounds__(256)
k_prep_csr(const float* __restrict__ w1, const float* __restrict__ w2,
           const float* __restrict__ w3, const float* __restrict__ g1,
           const float* __restrict__ b1, const float* __restrict__ be1,
           u16* __restrict__ wbf1, u16* __restrict__ wbf2,
           u16* __restrict__ wbf3, float* __restrict__ bias1,
           u16* __restrict__ list, int* __restrict__ coff,
           int* __restrict__ woff) {
#pragma clang fp contract(off)
  __shared__ unsigned char sidx[HW];            // 10000 B
  __shared__ unsigned short rowcnt[100][100];   // 20000 B
  __shared__ int off[NR + 1];
  __shared__ int wstart[17];
  int b = blockIdx.x;
  int t = threadIdx.x;

  if (b >= 100) {                               // ---- prep part ----
    int tt = (b - 100) * 256 + t;               // 0..147455
    if (tt < 32768) {
      int j = tt & 7, lp = (tt >> 3) & 63, nf = (tt >> 9) & 7, kc = tt >> 12;
      int co = nf * 16 + (lp & 15);
      int ci = kc * 32 + (lp >> 4) * 8 + j;
      float s = g1[co] / sqrtf(1.f + 1e-5f);
      wbf1[tt] = f2bf(w1[co * CIN + ci] * s);
    }
    if (b == 100 && t < 128) {
      float s = g1[t] / sqrtf(1.f + 1e-5f);
      bias1[t] = b1[t] * s + be1[t];
    }
    {
      int j = tt & 7, lp = (tt >> 3) & 63, nf = (tt >> 9) & 7, kc = (tt >> 12) & 3, tap = tt >> 14;
      int co = nf * 16 + (lp & 15);
      int ci = kc * 32 + (lp >> 4) * 8 + j;
      wbf2[tt] = f2bf(w2[(co * CH + ci) * 9 + tap]);
      wbf3[tt] = f2bf(w3[(co * CH + ci) * 9 + tap]);
    }
    return;
  }

  // ---- csr part (block = angle) ----
  int a = b;
  double theta = (double)a * (M_PI / 100.0);
  double irho  = 142.0 / 99.0;   // (floor(sqrt(2*100^2))+1)/(numRho-1)
  double ct = cos(theta) / irho;
  double st = sin(theta) / irho;

  if (t < 100) {
    for (int q = 0; q < 50; ++q) ((unsigned int*)&rowcnt[t][0])[q] = 0;
    int base = t * 100;
    for (int j = 0; j < 100; ++j) {
      double s = (double)(j - 50) * ct + (double)(t - 50) * st;
      int r = (int)rint(s) + 50;
      r = r < 0 ? 0 : (r > 99 ? 99 : r);
      sidx[base + j] = (unsigned char)r;
      rowcnt[t][r]++;
    }
  }
  if (t < 17) wstart[t] = NR;
  __syncthreads();

  if (t < 100) {
    int running = 0;
    for (int cc = 0; cc < 100; ++cc) {
      int tmp = rowcnt[cc][t];
      rowcnt[cc][t] = (unsigned short)running;
      running += tmp;
    }
    off[t + 1] = running;
  }
  __syncthreads();

  if (t == 0) {
    off[0] = 0;
    for (int bb = 0; bb < NR; ++bb) {
      int cb = off[bb + 1];
      off[bb + 1] = off[bb] + cb;
    }
  }
  __syncthreads();
  if (t <= NR) coff[a * (NR + 1) + t] = off[t];

  if (t < NR) {
    int o0 = off[t], o1 = off[t + 1];
    int ow = (o0 + ((o1 - o0) >> 1)) * 16 / HW;
    ow = ow > 15 ? 15 : ow;
    atomicMin(&wstart[ow], t);
  }
  __syncthreads();
  if (t == 0) {
    wstart[16] = NR;
    for (int ww = 15; ww >= 0; --ww)
      if (wstart[ww] == NR) wstart[ww] = wstart[ww + 1];
  }
  __syncthreads();
  if (t < 17) woff[a * 20 + t] = wstart[t];

  if (t < 100) {
    u16* dst = list + (size_t)a * HW;
    int base = t * 100;
    for (int j = 0; j < 100; ++j) {
      int r = sidx[base + j];
      int pos = off[r] + rowcnt[t][r];
      rowcnt[t][r]++;
      dst[pos] = (u16)(base + j);
    }
  }
}

// ---------------------------------------------------------------------------
// conv1 v3b: operand-swapped GEMM; x read with NON-TEMPORAL loads (single-use
// stream, keeps L2 clean). (unchanged from R17 attempt)
// ---------------------------------------------------------------------------
__global__ void __launch_bounds__(512)
k_conv1(const float* __restrict__ x, const u16* __restrict__ wbf1,
        const float* __restrict__ bias1, u16* __restrict__ h1t) {
  __shared__ char lds[32768];
  int n   = blockIdx.y;
  int hw0 = blockIdx.x * 128;
  int t   = threadIdx.x;
  int l   = t & 63, w = t >> 6, wm = w >> 2, wn = w & 3;

  const float* xn = x + (size_t)n * CIN * HW;
  int hwb  = hw0 + wn * 32 + (l & 15);
  int cinb = (l >> 4) * 8;

  f32x4 acc[4][2];
  f32x4 zf = {0.f, 0.f, 0.f, 0.f};
#pragma unroll
  for (int i = 0; i < 4; ++i)
#pragma unroll
    for (int j = 0; j < 2; ++j) acc[i][j] = zf;

  for (int kc = 0; kc < 8; ++kc) {
    short8 afr[4];
#pragma unroll
    for (int fm = 0; fm < 4; ++fm)
      afr[fm] = *(const short8*)(wbf1 + (((size_t)kc * 8 + wm * 4 + fm) * 64 + l) * 8);
    short8 bfr[2];
#pragma unroll
    for (int fn = 0; fn < 2; ++fn) {
      int hw = hwb + fn * 16;
      const float* col = xn + (size_t)(kc * 32 + cinb) * HW + hw;
      u16 vals[8];
      if (hw < HW) {
#pragma unroll
        for (int j = 0; j < 8; ++j)
          vals[j] = f2bf(__builtin_nontemporal_load(col + (size_t)j * HW));
      } else {
#pragma unroll
        for (int j = 0; j < 8; ++j) vals[j] = 0;
      }
      bfr[fn] = *(const short8*)vals;
    }
#pragma unroll
    for (int fm = 0; fm < 4; ++fm)
#pragma unroll
      for (int fn = 0; fn < 2; ++fn)
        acc[fm][fn] = __builtin_amdgcn_mfma_f32_16x16x32_bf16(afr[fm], bfr[fn], acc[fm][fn], 0, 0, 0);
  }

  float bi[4][4];
#pragma unroll
  for (int fm = 0; fm < 4; ++fm)
#pragma unroll
    for (int q = 0; q < 4; ++q)
      bi[fm][q] = bias1[wm * 64 + fm * 16 + (l >> 4) * 4 + q];

#pragma unroll
  for (int fm = 0; fm < 4; ++fm)
#pragma unroll
    for (int fn = 0; fn < 2; ++fn) {
      int mrow = wn * 32 + fn * 16 + (l & 15);
#pragma unroll
      for (int q = 0; q < 4; ++q) {
        int co = wm * 64 + fm * 16 + (l >> 4) * 4 + q;
        float y = fmaxf(acc[fm][fn][q] + bi[fm][q], 0.f);
        *(u16*)(lds + mrow * 256 + ((co * 2) ^ ((mrow & 15) << 4))) = f2bf(y);
      }
    }
  __syncthreads();
#pragma unroll
  for (int p = 0; p < 4; ++p) {
    int e = p * 512 + t;
    int m = e >> 4;
    int hw = hw0 + m;
    if (hw < HW) {
      uint4 v = *(const uint4*)(lds + m * 256 + (((e & 15) * 16) ^ ((m & 15) << 4)));
      *(uint4*)(h1t + ((size_t)n * HW + hw) * CH + (e & 15) * 8) = v;
    }
  }
}

// ---------------------------------------------------------------------------
// dht v9: v8 + NON-TEMPORAL output stores (scalar u32 — compiles fine).
// ---------------------------------------------------------------------------
__global__ void __launch_bounds__(256)
k_dht(const u16* __restrict__ h1t, const u16* __restrict__ list,
      const int* __restrict__ coff, const int* __restrict__ woff,
      u16* __restrict__ dht) {
  int id  = blockIdx.x;            // 0..6399
  int x   = id & 7;                // XCD
  int rem = id >> 3;               // 0..799
  int hi  = rem >= 400;
  int n   = (x << 1) | hi;
  int aq  = hi ? rem - 400 : rem;  // 0..399
  int a   = aq >> 2;
  int q   = aq & 3;
  int t   = threadIdx.x;
  int c   = t & 63;
  int w   = (t >> 6) + q * 4;

  const char* nimg = (const char*)h1t + (size_t)n * HW * 256;
  const int  c4    = c * 4;
  const u16* lst   = list + (size_t)a * HW;
  const int* cof   = coff + a * (NR + 1);
  const int* wof   = woff + a * 20;
  unsigned int* out32 = (unsigned int*)(dht + ((size_t)(n * NA + a) * NR) * CH) + c;

  int rlo = __builtin_amdgcn_readfirstlane(wof[w]);
  int rhi = __builtin_amdgcn_readfirstlane(wof[w + 1]);
  if (rlo >= rhi) return;

  int o0 = __builtin_amdgcn_readfirstlane(cof[rlo]);
  for (int r = rlo; r < rhi; ++r) {
    int o1 = __builtin_amdgcn_readfirstlane(cof[r + 1]);

    f32x2 A0 = {0.f, 0.f}, A1 = {0.f, 0.f};
    int k = o0;

    if (k & 1) {
      int p = __builtin_amdgcn_readfirstlane((int)lst[k]);
      unsigned int v = *(const unsigned int*)((nimg + ((size_t)p << 8)) + c4);
      A0 += bfpair(v);
      ++k;
    }

    for (; k + 16 <= o1; k += 16) {
      unsigned int ids[8];
#pragma unroll
      for (int j = 0; j < 8; ++j)
        ids[j] = __builtin_amdgcn_readfirstlane(*(const unsigned int*)(lst + k + 2 * j));
      unsigned int v[16];
#pragma unroll
      for (int j = 0; j < 8; ++j) {
        int p0 = (int)(ids[j] & 0xffffu);
        int p1 = (int)(ids[j] >> 16);
        v[2 * j]     = *(const unsigned int*)((nimg + ((size_t)p0 << 8)) + c4);
        v[2 * j + 1] = *(const unsigned int*)((nimg + ((size_t)p1 << 8)) + c4);
      }
#pragma unroll
      for (int j = 0; j < 16; ++j) {
        if (j & 1) A1 += bfpair(v[j]);
        else       A0 += bfpair(v[j]);
      }
    }
    for (; k + 2 <= o1; k += 2) {
      unsigned int ids = __builtin_amdgcn_readfirstlane(*(const unsigned int*)(lst + k));
      int p0 = (int)(ids & 0xffffu);
      int p1 = (int)(ids >> 16);
      unsigned int v0 = *(const unsigned int*)((nimg + ((size_t)p0 << 8)) + c4);
      unsigned int v1 = *(const unsigned int*)((nimg + ((size_t)p1 << 8)) + c4);
      A0 += bfpair(v0);
      A1 += bfpair(v1);
    }
    if (k < o1) {
      int p = __builtin_amdgcn_readfirstlane((int)lst[k]);
      unsigned int v = *(const unsigned int*)((nimg + ((size_t)p << 8)) + c4);
      A0 += bfpair(v);
    }

    float ax = A0.x + A1.x;
    float ay = A0.y + A1.y;
    unsigned int pk = (unsigned int)f2bf(ax) | ((unsigned int)f2bf(ay) << 16);
    __builtin_nontemporal_store(pk, &out32[(size_t)r << 6]);
    o0 = o1;
  }
}

// ---------------------------------------------------------------------------
// conv3x3 (MFMA implicit GEMM, 8 waves, 16x16 frags) — R16 + NT output stores
// via ext_vector types (u32x4 / f32x4) to satisfy the builtin's pointer rules.
// ---------------------------------------------------------------------------
template <int OUT_MODE>
__global__ void __launch_bounds__(512)
k_conv3x3(const u16* __restrict__ X, const u16* __restrict__ wbf,
          const float* __restrict__ pb, const float* __restrict__ pg,
          const float* __restrict__ pbe, void* __restrict__ out) {
  __shared__ uint4 lds4[2880];               // 46080 B
  char* lds = (char*)lds4;
  int n    = blockIdx.y;
  int tile = blockIdx.x;
  int ta = tile / 13, tr = tile - ta * 13;
  int a0 = ta * 16, r0 = tr * 8;
  int t  = threadIdx.x;
  int l  = t & 63, w = t >> 6, wm = w >> 2, wn = w & 3;

  {
    int sr32 = t >> 4;
    int cb   = (t & 15) * 16;
#pragma unroll
    for (int p = 0; p < 6; ++p) {
      int s = p * 32 + sr32;
      if (s < 180) {
        int sa = a0 - 1 + s / 10;
        int sr = r0 - 1 + s % 10;
        uint4 v = make_uint4(0, 0, 0, 0);
        if (sa >= 0 && sa < NA && sr >= 0 && sr < NR)
          v = *(const uint4*)(X + ((size_t)(n * NA + sa) * NR + sr) * CH + (t & 15) * 8);
        *(uint4*)(lds + s * 256 + (cb ^ ((s & 15) << 4))) = v;
      }
    }
  }
  __syncthreads();

  int sbase[4];
#pragma unroll
  for (int fm = 0; fm < 4; ++fm) {
    int m = wm * 64 + fm * 16 + (l & 15);
    sbase[fm] = ((m >> 3) + 1) * 10 + (m & 7) + 1;
  }
  int kseg = (l >> 4) * 16;

  f32x4 acc[4][2];
  f32x4 zf = {0.f, 0.f, 0.f, 0.f};
#pragma unroll
  for (int i = 0; i < 4; ++i)
#pragma unroll
    for (int j = 0; j < 2; ++j) acc[i][j] = zf;

  for (int tap = 0; tap < 9; ++tap) {
    int soff = (tap / 3 - 1) * 10 + (tap % 3 - 1);
#pragma unroll
    for (int kc = 0; kc < 4; ++kc) {
      short8 afr[4], bfr[2];
#pragma unroll
      for (int fm = 0; fm < 4; ++fm) {
        int s = sbase[fm] + soff;
        afr[fm] = *(const short8*)(lds + s * 256 + ((kc * 64 + kseg) ^ ((s & 15) << 4)));
      }
#pragma unroll
      for (int fn = 0; fn < 2; ++fn)
        bfr[fn] = *(const short8*)(wbf + (((size_t)(tap * 4 + kc) * 8 + wn * 2 + fn) * 64 + l) * 8);
#pragma unroll
      for (int fm = 0; fm < 4; ++fm)
#pragma unroll
        for (int fn = 0; fn < 2; ++fn)
          acc[fm][fn] = __builtin_amdgcn_mfma_f32_16x16x32_bf16(afr[fm], bfr[fn], acc[fm][fn], 0, 0, 0);
    }
  }

  float sc[2], sh[2];
#pragma unroll
  for (int fn = 0; fn < 2; ++fn) {
    int co = wn * 32 + fn * 16 + (l & 15);
    float s = pg[co] / sqrtf(1.f + 1e-5f);
    sc[fn] = s;
    sh[fn] = pb[co] * s + pbe[co];
  }

  if (OUT_MODE == 0) {
    __syncthreads();
#pragma unroll
    for (int fm = 0; fm < 4; ++fm)
#pragma unroll
      for (int fn = 0; fn < 2; ++fn) {
        int co = wn * 32 + fn * 16 + (l & 15);
#pragma unroll
        for (int q = 0; q < 4; ++q) {
          int m = wm * 64 + fm * 16 + (l >> 4) * 4 + q;
          float y = fmaxf(acc[fm][fn][q] * sc[fn] + sh[fn], 0.f);
          *(u16*)(lds + m * 256 + ((co * 2) ^ ((m & 15) << 4))) = f2bf(y);
        }
      }
    __syncthreads();
    u16* o = (u16*)out;
#pragma unroll
    for (int p = 0; p < 4; ++p) {
      int e = p * 512 + t;
      int m = e >> 4;
      int a = a0 + (m >> 3), r = r0 + (m & 7);
      if (a < NA && r < NR) {
        u32x4 v = *(const u32x4*)(lds + m * 256 + (((e & 15) * 16) ^ ((m & 15) << 4)));
        __builtin_nontemporal_store(v, (u32x4*)(o + ((size_t)(n * NA + a) * NR + r) * CH + (e & 15) * 8));
      }
    }
  } else {
    float* o = (float*)out;
#pragma unroll
    for (int fm = 0; fm < 4; ++fm) {
      int mb = wm * 64 + fm * 16 + (l >> 4) * 4;
      int a  = a0 + (mb >> 3), rr = r0 + (mb & 7);
      if (a < NA && rr < NR) {
#pragma unroll
        for (int fn = 0; fn < 2; ++fn) {
          int co = wn * 32 + fn * 16 + (l & 15);
          f32x4 v;
          v.x = fmaxf(acc[fm][fn][0] * sc[fn] + sh[fn], 0.f);
          v.y = fmaxf(acc[fm][fn][1] * sc[fn] + sh[fn], 0.f);
          v.z = fmaxf(acc[fm][fn][2] * sc[fn] + sh[fn], 0.f);
          v.w = fmaxf(acc[fm][fn][3] * sc[fn] + sh[fn], 0.f);
          __builtin_nontemporal_store(v, (f32x4*)(o + ((size_t)n * CH + co) * HW + a * NR + rr));
        }
      }
    }
  }
}

// ---------------------------------------------------------------------------
extern "C" void kernel_launch(void* const* d_in, const int* in_sizes, int n_in,
                              void* d_out, int out_size, void* d_ws, size_t ws_size,
                              hipStream_t stream) {
  if (n_in < 13) return;
  const float* x   = (const float*)d_in[0];
  const float* w1  = (const float*)d_in[1];
  const float* b1  = (const float*)d_in[2];
  const float* g1  = (const float*)d_in[3];
  const float* be1 = (const float*)d_in[4];
  const float* w2  = (const float*)d_in[5];
  const float* b2  = (const float*)d_in[6];
  const float* g2  = (const float*)d_in[7];
  const float* be2 = (const float*)d_in[8];
  const float* w3  = (const float*)d_in[9];
  const float* b3  = (const float*)d_in[10];
  const float* g3  = (const float*)d_in[11];
  const float* be3 = (const float*)d_in[12];

  // workspace layout (256B-aligned)
  const size_t o_list  = 0;                    // u16[100][10000]     = 2,000,000
  const size_t o_coff  = 2000128;              // int[100][101]       =    40,400
  const size_t o_woff  = 2040576;              // int[100][20]        =     8,000
  const size_t o_wbf1  = 2048768;              // u16[32768]          =    65,536
  const size_t o_wbf2  = o_wbf1 + 65536;       // u16[147456]         =   294,912
  const size_t o_wbf3  = o_wbf2 + 294912;      // u16[147456]         =   294,912
  const size_t o_bias1 = o_wbf3 + 294912;      // f32[128]            =       512 (pad 1024)
  const size_t o_dht   = o_bias1 + 1024;       // 40,960,000
  const size_t o_c2    = o_dht + 40960000;     // 40,960,000
  const size_t need    = o_c2 + 40960000;      // ~84.6 MB
  if (ws_size < need) return;

  char*  ws    = (char*)d_ws;
  u16*   list  = (u16*)(ws + o_list);
  int*   coff  = (int*)(ws + o_coff);
  int*   woff  = (int*)(ws + o_woff);
  u16*   wbf1  = (u16*)(ws + o_wbf1);
  u16*   wbf2  = (u16*)(ws + o_wbf2);
  u16*   wbf3  = (u16*)(ws + o_wbf3);
  float* bias1 = (float*)(ws + o_bias1);
  u16*   dht   = (u16*)(ws + o_dht);
  u16*   c2    = (u16*)(ws + o_c2);
  u16*   h1t   = (u16*)d_out;   // bf16 scratch inside f32 out (dead before conv3)

  k_prep_csr<<<dim3(676), dim3(256), 0, stream>>>(w1, w2, w3, g1, b1, be1,
                                                  wbf1, wbf2, wbf3, bias1,
                                                  list, coff, woff);
  k_conv1<<<dim3(79, 16), dim3(512), 0, stream>>>(x, wbf1, bias1, h1t);
  k_dht<<<dim3(6400), dim3(256), 0, stream>>>(h1t, list, coff, woff, dht);
  k_conv3x3<0><<<dim3(91, 16), dim3(512), 0, stream>>>(dht, wbf2, b2, g2, be2, (void*)c2);
  k_conv3x3<1><<<dim3(91, 16), dim3(512), 0, stream>>>(c2, wbf3, b3, g3, be3, d_out);
}

// Round 19
// 417.806 us; speedup vs baseline: 1.0654x; 1.0654x over previous
//
#include <hip/hip_runtime.h>
#include <hip/hip_bf16.h>
#include <math.h>

#ifndef M_PI
#define M_PI 3.14159265358979323846
#endif

typedef unsigned short u16;
typedef short short8 __attribute__((ext_vector_type(8)));
typedef float f32x4 __attribute__((ext_vector_type(4)));
typedef float f32x2 __attribute__((ext_vector_type(2)));

#define CIN  256
#define CH   128
#define HW   10000
#define NA   100
#define NR   100

__device__ __forceinline__ float bf2f(u16 v) {
  return __uint_as_float(((unsigned int)v) << 16);
}
__device__ __forceinline__ u16 f2bf(float f) {
  unsigned int u = __float_as_uint(f);
  u += 0x7fffu + ((u >> 16) & 1u);   // round-to-nearest-even
  return (u16)(u >> 16);
}
__device__ __forceinline__ f32x2 bfpair(unsigned int v) {
  f32x2 r;
  r.x = __uint_as_float(v << 16);
  r.y = __uint_as_float(v & 0xffff0000u);
  return r;
}

// ---------------------------------------------------------------------------
// prep+csr merged: blocks 0..99 csr (+ per-wave bin ranges); 100..675 weights.
// wbf1 pre-scaled by BN scale; bias1 = b1*s + be1. (R16)
// ---------------------------------------------------------------------------
__global__ void __launch_bounds__(256)
k_prep_csr(const float* __restrict__ w1, const float* __restrict__ w2,
           const float* __restrict__ w3, const float* __restrict__ g1,
           const float* __restrict__ b1, const float* __restrict__ be1,
           u16* __restrict__ wbf1, u16* __restrict__ wbf2,
           u16* __restrict__ wbf3, float* __restrict__ bias1,
           u16* __restrict__ list, int* __restrict__ coff,
           int* __restrict__ woff) {
#pragma clang fp contract(off)
  __shared__ unsigned char sidx[HW];            // 10000 B
  __shared__ unsigned short rowcnt[100][100];   // 20000 B
  __shared__ int off[NR + 1];
  __shared__ int wstart[17];
  int b = blockIdx.x;
  int t = threadIdx.x;

  if (b >= 100) {                               // ---- prep part ----
    int tt = (b - 100) * 256 + t;               // 0..147455
    if (tt < 32768) {
      int j = tt & 7, lp = (tt >> 3) & 63, nf = (tt >> 9) & 7, kc = tt >> 12;
      int co = nf * 16 + (lp & 15);
      int ci = kc * 32 + (lp >> 4) * 8 + j;
      float s = g1[co] / sqrtf(1.f + 1e-5f);
      wbf1[tt] = f2bf(w1[co * CIN + ci] * s);
    }
    if (b == 100 && t < 128) {
      float s = g1[t] / sqrtf(1.f + 1e-5f);
      bias1[t] = b1[t] * s + be1[t];
    }
    {
      int j = tt & 7, lp = (tt >> 3) & 63, nf = (tt >> 9) & 7, kc = (tt >> 12) & 3, tap = tt >> 14;
      int co = nf * 16 + (lp & 15);
      int ci = kc * 32 + (lp >> 4) * 8 + j;
      wbf2[tt] = f2bf(w2[(co * CH + ci) * 9 + tap]);
      wbf3[tt] = f2bf(w3[(co * CH + ci) * 9 + tap]);
    }
    return;
  }

  // ---- csr part (block = angle) ----
  int a = b;
  double theta = (double)a * (M_PI / 100.0);
  double irho  = 142.0 / 99.0;   // (floor(sqrt(2*100^2))+1)/(numRho-1)
  double ct = cos(theta) / irho;
  double st = sin(theta) / irho;

  if (t < 100) {
    for (int q = 0; q < 50; ++q) ((unsigned int*)&rowcnt[t][0])[q] = 0;
    int base = t * 100;
    for (int j = 0; j < 100; ++j) {
      double s = (double)(j - 50) * ct + (double)(t - 50) * st;
      int r = (int)rint(s) + 50;
      r = r < 0 ? 0 : (r > 99 ? 99 : r);
      sidx[base + j] = (unsigned char)r;
      rowcnt[t][r]++;
    }
  }
  if (t < 17) wstart[t] = NR;
  __syncthreads();

  if (t < 100) {
    int running = 0;
    for (int cc = 0; cc < 100; ++cc) {
      int tmp = rowcnt[cc][t];
      rowcnt[cc][t] = (unsigned short)running;
      running += tmp;
    }
    off[t + 1] = running;
  }
  __syncthreads();

  if (t == 0) {
    off[0] = 0;
    for (int bb = 0; bb < NR; ++bb) {
      int cb = off[bb + 1];
      off[bb + 1] = off[bb] + cb;
    }
  }
  __syncthreads();
  if (t <= NR) coff[a * (NR + 1) + t] = off[t];

  if (t < NR) {
    int o0 = off[t], o1 = off[t + 1];
    int ow = (o0 + ((o1 - o0) >> 1)) * 16 / HW;
    ow = ow > 15 ? 15 : ow;
    atomicMin(&wstart[ow], t);
  }
  __syncthreads();
  if (t == 0) {
    wstart[16] = NR;
    for (int ww = 15; ww >= 0; --ww)
      if (wstart[ww] == NR) wstart[ww] = wstart[ww + 1];
  }
  __syncthreads();
  if (t < 17) woff[a * 20 + t] = wstart[t];

  if (t < 100) {
    u16* dst = list + (size_t)a * HW;
    int base = t * 100;
    for (int j = 0; j < 100; ++j) {
      int r = sidx[base + j];
      int pos = off[r] + rowcnt[t][r];
      rowcnt[t][r]++;
      dst[pos] = (u16)(base + j);
    }
  }
}

// ---------------------------------------------------------------------------
// conv1 v3 (operand-swapped, plain loads — R16 state): M=co, N=hw, K=cin.
// ---------------------------------------------------------------------------
__global__ void __launch_bounds__(512)
k_conv1(const float* __restrict__ x, const u16* __restrict__ wbf1,
        const float* __restrict__ bias1, u16* __restrict__ h1t) {
  __shared__ char lds[32768];
  int n   = blockIdx.y;
  int hw0 = blockIdx.x * 128;
  int t   = threadIdx.x;
  int l   = t & 63, w = t >> 6, wm = w >> 2, wn = w & 3;

  const float* xn = x + (size_t)n * CIN * HW;
  int hwb  = hw0 + wn * 32 + (l & 15);
  int cinb = (l >> 4) * 8;

  f32x4 acc[4][2];
  f32x4 zf = {0.f, 0.f, 0.f, 0.f};
#pragma unroll
  for (int i = 0; i < 4; ++i)
#pragma unroll
    for (int j = 0; j < 2; ++j) acc[i][j] = zf;

  for (int kc = 0; kc < 8; ++kc) {
    short8 afr[4];
#pragma unroll
    for (int fm = 0; fm < 4; ++fm)
      afr[fm] = *(const short8*)(wbf1 + (((size_t)kc * 8 + wm * 4 + fm) * 64 + l) * 8);
    short8 bfr[2];
#pragma unroll
    for (int fn = 0; fn < 2; ++fn) {
      int hw = hwb + fn * 16;
      const float* col = xn + (size_t)(kc * 32 + cinb) * HW + hw;
      u16 vals[8];
      if (hw < HW) {
#pragma unroll
        for (int j = 0; j < 8; ++j) vals[j] = f2bf(col[(size_t)j * HW]);
      } else {
#pragma unroll
        for (int j = 0; j < 8; ++j) vals[j] = 0;
      }
      bfr[fn] = *(const short8*)vals;
    }
#pragma unroll
    for (int fm = 0; fm < 4; ++fm)
#pragma unroll
      for (int fn = 0; fn < 2; ++fn)
        acc[fm][fn] = __builtin_amdgcn_mfma_f32_16x16x32_bf16(afr[fm], bfr[fn], acc[fm][fn], 0, 0, 0);
  }

  float bi[4][4];
#pragma unroll
  for (int fm = 0; fm < 4; ++fm)
#pragma unroll
    for (int q = 0; q < 4; ++q)
      bi[fm][q] = bias1[wm * 64 + fm * 16 + (l >> 4) * 4 + q];

#pragma unroll
  for (int fm = 0; fm < 4; ++fm)
#pragma unroll
    for (int fn = 0; fn < 2; ++fn) {
      int mrow = wn * 32 + fn * 16 + (l & 15);
#pragma unroll
      for (int q = 0; q < 4; ++q) {
        int co = wm * 64 + fm * 16 + (l >> 4) * 4 + q;
        float y = fmaxf(acc[fm][fn][q] + bi[fm][q], 0.f);
        *(u16*)(lds + mrow * 256 + ((co * 2) ^ ((mrow & 15) << 4))) = f2bf(y);
      }
    }
  __syncthreads();
#pragma unroll
  for (int p = 0; p < 4; ++p) {
    int e = p * 512 + t;
    int m = e >> 4;
    int hw = hw0 + m;
    if (hw < HW) {
      uint4 v = *(const uint4*)(lds + m * 256 + (((e & 15) * 16) ^ ((m & 15) << 4)));
      *(uint4*)(h1t + ((size_t)n * HW + hw) * CH + (e & 15) * 8) = v;
    }
  }
}

// ---------------------------------------------------------------------------
// dht v8 (R16 state — plain stores; dht is re-read by conv3x3<0>, keep in L2).
// ---------------------------------------------------------------------------
__global__ void __launch_bounds__(256)
k_dht(const u16* __restrict__ h1t, const u16* __restrict__ list,
      const int* __restrict__ coff, const int* __restrict__ woff,
      u16* __restrict__ dht) {
  int id  = blockIdx.x;            // 0..6399
  int x   = id & 7;                // XCD
  int rem = id >> 3;               // 0..799
  int hi  = rem >= 400;
  int n   = (x << 1) | hi;
  int aq  = hi ? rem - 400 : rem;  // 0..399
  int a   = aq >> 2;
  int q   = aq & 3;
  int t   = threadIdx.x;
  int c   = t & 63;
  int w   = (t >> 6) + q * 4;

  const char* nimg = (const char*)h1t + (size_t)n * HW * 256;
  const int  c4    = c * 4;
  const u16* lst   = list + (size_t)a * HW;
  const int* cof   = coff + a * (NR + 1);
  const int* wof   = woff + a * 20;
  unsigned int* out32 = (unsigned int*)(dht + ((size_t)(n * NA + a) * NR) * CH) + c;

  int rlo = __builtin_amdgcn_readfirstlane(wof[w]);
  int rhi = __builtin_amdgcn_readfirstlane(wof[w + 1]);
  if (rlo >= rhi) return;

  int o0 = __builtin_amdgcn_readfirstlane(cof[rlo]);
  for (int r = rlo; r < rhi; ++r) {
    int o1 = __builtin_amdgcn_readfirstlane(cof[r + 1]);

    f32x2 A0 = {0.f, 0.f}, A1 = {0.f, 0.f};
    int k = o0;

    if (k & 1) {
      int p = __builtin_amdgcn_readfirstlane((int)lst[k]);
      unsigned int v = *(const unsigned int*)((nimg + ((size_t)p << 8)) + c4);
      A0 += bfpair(v);
      ++k;
    }

    for (; k + 16 <= o1; k += 16) {
      unsigned int ids[8];
#pragma unroll
      for (int j = 0; j < 8; ++j)
        ids[j] = __builtin_amdgcn_readfirstlane(*(const unsigned int*)(lst + k + 2 * j));
      unsigned int v[16];
#pragma unroll
      for (int j = 0; j < 8; ++j) {
        int p0 = (int)(ids[j] & 0xffffu);
        int p1 = (int)(ids[j] >> 16);
        v[2 * j]     = *(const unsigned int*)((nimg + ((size_t)p0 << 8)) + c4);
        v[2 * j + 1] = *(const unsigned int*)((nimg + ((size_t)p1 << 8)) + c4);
      }
#pragma unroll
      for (int j = 0; j < 16; ++j) {
        if (j & 1) A1 += bfpair(v[j]);
        else       A0 += bfpair(v[j]);
      }
    }
    for (; k + 2 <= o1; k += 2) {
      unsigned int ids = __builtin_amdgcn_readfirstlane(*(const unsigned int*)(lst + k));
      int p0 = (int)(ids & 0xffffu);
      int p1 = (int)(ids >> 16);
      unsigned int v0 = *(const unsigned int*)((nimg + ((size_t)p0 << 8)) + c4);
      unsigned int v1 = *(const unsigned int*)((nimg + ((size_t)p1 << 8)) + c4);
      A0 += bfpair(v0);
      A1 += bfpair(v1);
    }
    if (k < o1) {
      int p = __builtin_amdgcn_readfirstlane((int)lst[k]);
      unsigned int v = *(const unsigned int*)((nimg + ((size_t)p << 8)) + c4);
      A0 += bfpair(v);
    }

    float ax = A0.x + A1.x;
    float ay = A0.y + A1.y;
    unsigned int pk = (unsigned int)f2bf(ax) | ((unsigned int)f2bf(ay) << 16);
    out32[(size_t)r << 6] = pk;
    o0 = o1;
  }
}

// ---------------------------------------------------------------------------
// conv3x3 (MFMA implicit GEMM, 8 waves, 16x16 frags) — R16 state; the ONLY
// NT store is MODE1's d_out (final output, never re-read -> keep L2 clean).
// MODE0's c2 stores stay regular (re-read by the next dispatch).
// ---------------------------------------------------------------------------
template <int OUT_MODE>
__global__ void __launch_bounds__(512)
k_conv3x3(const u16* __restrict__ X, const u16* __restrict__ wbf,
          const float* __restrict__ pb, const float* __restrict__ pg,
          const float* __restrict__ pbe, void* __restrict__ out) {
  __shared__ uint4 lds4[2880];               // 46080 B
  char* lds = (char*)lds4;
  int n    = blockIdx.y;
  int tile = blockIdx.x;
  int ta = tile / 13, tr = tile - ta * 13;
  int a0 = ta * 16, r0 = tr * 8;
  int t  = threadIdx.x;
  int l  = t & 63, w = t >> 6, wm = w >> 2, wn = w & 3;

  {
    int sr32 = t >> 4;
    int cb   = (t & 15) * 16;
#pragma unroll
    for (int p = 0; p < 6; ++p) {
      int s = p * 32 + sr32;
      if (s < 180) {
        int sa = a0 - 1 + s / 10;
        int sr = r0 - 1 + s % 10;
        uint4 v = make_uint4(0, 0, 0, 0);
        if (sa >= 0 && sa < NA && sr >= 0 && sr < NR)
          v = *(const uint4*)(X + ((size_t)(n * NA + sa) * NR + sr) * CH + (t & 15) * 8);
        *(uint4*)(lds + s * 256 + (cb ^ ((s & 15) << 4))) = v;
      }
    }
  }
  __syncthreads();

  int sbase[4];
#pragma unroll
  for (int fm = 0; fm < 4; ++fm) {
    int m = wm * 64 + fm * 16 + (l & 15);
    sbase[fm] = ((m >> 3) + 1) * 10 + (m & 7) + 1;
  }
  int kseg = (l >> 4) * 16;

  f32x4 acc[4][2];
  f32x4 zf = {0.f, 0.f, 0.f, 0.f};
#pragma unroll
  for (int i = 0; i < 4; ++i)
#pragma unroll
    for (int j = 0; j < 2; ++j) acc[i][j] = zf;

  for (int tap = 0; tap < 9; ++tap) {
    int soff = (tap / 3 - 1) * 10 + (tap % 3 - 1);
#pragma unroll
    for (int kc = 0; kc < 4; ++kc) {
      short8 afr[4], bfr[2];
#pragma unroll
      for (int fm = 0; fm < 4; ++fm) {
        int s = sbase[fm] + soff;
        afr[fm] = *(const short8*)(lds + s * 256 + ((kc * 64 + kseg) ^ ((s & 15) << 4)));
      }
#pragma unroll
      for (int fn = 0; fn < 2; ++fn)
        bfr[fn] = *(const short8*)(wbf + (((size_t)(tap * 4 + kc) * 8 + wn * 2 + fn) * 64 + l) * 8);
#pragma unroll
      for (int fm = 0; fm < 4; ++fm)
#pragma unroll
        for (int fn = 0; fn < 2; ++fn)
          acc[fm][fn] = __builtin_amdgcn_mfma_f32_16x16x32_bf16(afr[fm], bfr[fn], acc[fm][fn], 0, 0, 0);
    }
  }

  float sc[2], sh[2];
#pragma unroll
  for (int fn = 0; fn < 2; ++fn) {
    int co = wn * 32 + fn * 16 + (l & 15);
    float s = pg[co] / sqrtf(1.f + 1e-5f);
    sc[fn] = s;
    sh[fn] = pb[co] * s + pbe[co];
  }

  if (OUT_MODE == 0) {
    __syncthreads();
#pragma unroll
    for (int fm = 0; fm < 4; ++fm)
#pragma unroll
      for (int fn = 0; fn < 2; ++fn) {
        int co = wn * 32 + fn * 16 + (l & 15);
#pragma unroll
        for (int q = 0; q < 4; ++q) {
          int m = wm * 64 + fm * 16 + (l >> 4) * 4 + q;
          float y = fmaxf(acc[fm][fn][q] * sc[fn] + sh[fn], 0.f);
          *(u16*)(lds + m * 256 + ((co * 2) ^ ((m & 15) << 4))) = f2bf(y);
        }
      }
    __syncthreads();
    u16* o = (u16*)out;
#pragma unroll
    for (int p = 0; p < 4; ++p) {
      int e = p * 512 + t;
      int m = e >> 4;
      int a = a0 + (m >> 3), r = r0 + (m & 7);
      if (a < NA && r < NR) {
        uint4 v = *(const uint4*)(lds + m * 256 + (((e & 15) * 16) ^ ((m & 15) << 4)));
        *(uint4*)(o + ((size_t)(n * NA + a) * NR + r) * CH + (e & 15) * 8) = v;
      }
    }
  } else {
    float* o = (float*)out;
#pragma unroll
    for (int fm = 0; fm < 4; ++fm) {
      int mb = wm * 64 + fm * 16 + (l >> 4) * 4;
      int a  = a0 + (mb >> 3), rr = r0 + (mb & 7);
      if (a < NA && rr < NR) {
#pragma unroll
        for (int fn = 0; fn < 2; ++fn) {
          int co = wn * 32 + fn * 16 + (l & 15);
          f32x4 v;
          v.x = fmaxf(acc[fm][fn][0] * sc[fn] + sh[fn], 0.f);
          v.y = fmaxf(acc[fm][fn][1] * sc[fn] + sh[fn], 0.f);
          v.z = fmaxf(acc[fm][fn][2] * sc[fn] + sh[fn], 0.f);
          v.w = fmaxf(acc[fm][fn][3] * sc[fn] + sh[fn], 0.f);
          __builtin_nontemporal_store(v, (f32x4*)(o + ((size_t)n * CH + co) * HW + a * NR + rr));
        }
      }
    }
  }
}

// ---------------------------------------------------------------------------
extern "C" void kernel_launch(void* const* d_in, const int* in_sizes, int n_in,
                              void* d_out, int out_size, void* d_ws, size_t ws_size,
                              hipStream_t stream) {
  if (n_in < 13) return;
  const float* x   = (const float*)d_in[0];
  const float* w1  = (const float*)d_in[1];
  const float* b1  = (const float*)d_in[2];
  const float* g1  = (const float*)d_in[3];
  const float* be1 = (const float*)d_in[4];
  const float* w2  = (const float*)d_in[5];
  const float* b2  = (const float*)d_in[6];
  const float* g2  = (const float*)d_in[7];
  const float* be2 = (const float*)d_in[8];
  const float* w3  = (const float*)d_in[9];
  const float* b3  = (const float*)d_in[10];
  const float* g3  = (const float*)d_in[11];
  const float* be3 = (const float*)d_in[12];

  // workspace layout (256B-aligned)
  const size_t o_list  = 0;                    // u16[100][10000]     = 2,000,000
  const size_t o_coff  = 2000128;              // int[100][101]       =    40,400
  const size_t o_woff  = 2040576;              // int[100][20]        =     8,000
  const size_t o_wbf1  = 2048768;              // u16[32768]          =    65,536
  const size_t o_wbf2  = o_wbf1 + 65536;       // u16[147456]         =   294,912
  const size_t o_wbf3  = o_wbf2 + 294912;      // u16[147456]         =   294,912
  const size_t o_bias1 = o_wbf3 + 294912;      // f32[128]            =       512 (pad 1024)
  const size_t o_dht   = o_bias1 + 1024;       // 40,960,000
  const size_t o_c2    = o_dht + 40960000;     // 40,960,000
  const size_t need    = o_c2 + 40960000;      // ~84.6 MB
  if (ws_size < need) return;

  char*  ws    = (char*)d_ws;
  u16*   list  = (u16*)(ws + o_list);
  int*   coff  = (int*)(ws + o_coff);
  int*   woff  = (int*)(ws + o_woff);
  u16*   wbf1  = (u16*)(ws + o_wbf1);
  u16*   wbf2  = (u16*)(ws + o_wbf2);
  u16*   wbf3  = (u16*)(ws + o_wbf3);
  float* bias1 = (float*)(ws + o_bias1);
  u16*   dht   = (u16*)(ws + o_dht);
  u16*   c2    = (u16*)(ws + o_c2);
  u16*   h1t   = (u16*)d_out;   // bf16 scratch inside f32 out (dead before conv3)

  k_prep_csr<<<dim3(676), dim3(256), 0, stream>>>(w1, w2, w3, g1, b1, be1,
                                                  wbf1, wbf2, wbf3, bias1,
                                                  list, coff, woff);
  k_conv1<<<dim3(79, 16), dim3(512), 0, stream>>>(x, wbf1, bias1, h1t);
  k_dht<<<dim3(6400), dim3(256), 0, stream>>>(h1t, list, coff, woff, dht);
  k_conv3x3<0><<<dim3(91, 16), dim3(512), 0, stream>>>(dht, wbf2, b2, g2, be2, (void*)c2);
  k_conv3x3<1><<<dim3(91, 16), dim3(512), 0, stream>>>(c2, wbf3, b3, g3, be3, d_out);
}

// Round 20
// 391.662 us; speedup vs baseline: 1.1365x; 1.0668x over previous
//
#include <hip/hip_runtime.h>
#include <hip/hip_bf16.h>
#include <math.h>

#ifndef M_PI
#define M_PI 3.14159265358979323846
#endif

typedef unsigned short u16;
typedef short short8 __attribute__((ext_vector_type(8)));
typedef float f32x4 __attribute__((ext_vector_type(4)));
typedef float f32x2 __attribute__((ext_vector_type(2)));

#define CIN  256
#define CH   128
#define HW   10000
#define NA   100
#define NR   100

__device__ __forceinline__ float bf2f(u16 v) {
  return __uint_as_float(((unsigned int)v) << 16);
}
__device__ __forceinline__ u16 f2bf(float f) {
  unsigned int u = __float_as_uint(f);
  u += 0x7fffu + ((u >> 16) & 1u);   // round-to-nearest-even
  return (u16)(u >> 16);
}
__device__ __forceinline__ f32x2 bfpair(unsigned int v) {
  f32x2 r;
  r.x = __uint_as_float(v << 16);
  r.y = __uint_as_float(v & 0xffff0000u);
  return r;
}

// ---------------------------------------------------------------------------
// prep+csr merged: blocks 0..99 csr (+ per-wave bin ranges); 100..675 weights.
// wbf1 pre-scaled by BN scale; bias1 = b1*s + be1. (R16 state)
// ---------------------------------------------------------------------------
__global__ void __launch_bounds__(256)
k_prep_csr(const float* __restrict__ w1, const float* __restrict__ w2,
           const float* __restrict__ w3, const float* __restrict__ g1,
           const float* __restrict__ b1, const float* __restrict__ be1,
           u16* __restrict__ wbf1, u16* __restrict__ wbf2,
           u16* __restrict__ wbf3, float* __restrict__ bias1,
           u16* __restrict__ list, int* __restrict__ coff,
           int* __restrict__ woff) {
#pragma clang fp contract(off)
  __shared__ unsigned char sidx[HW];            // 10000 B
  __shared__ unsigned short rowcnt[100][100];   // 20000 B
  __shared__ int off[NR + 1];
  __shared__ int wstart[17];
  int b = blockIdx.x;
  int t = threadIdx.x;

  if (b >= 100) {                               // ---- prep part ----
    int tt = (b - 100) * 256 + t;               // 0..147455
    if (tt < 32768) {
      int j = tt & 7, lp = (tt >> 3) & 63, nf = (tt >> 9) & 7, kc = tt >> 12;
      int co = nf * 16 + (lp & 15);
      int ci = kc * 32 + (lp >> 4) * 8 + j;
      float s = g1[co] / sqrtf(1.f + 1e-5f);
      wbf1[tt] = f2bf(w1[co * CIN + ci] * s);
    }
    if (b == 100 && t < 128) {
      float s = g1[t] / sqrtf(1.f + 1e-5f);
      bias1[t] = b1[t] * s + be1[t];
    }
    {
      int j = tt & 7, lp = (tt >> 3) & 63, nf = (tt >> 9) & 7, kc = (tt >> 12) & 3, tap = tt >> 14;
      int co = nf * 16 + (lp & 15);
      int ci = kc * 32 + (lp >> 4) * 8 + j;
      wbf2[tt] = f2bf(w2[(co * CH + ci) * 9 + tap]);
      wbf3[tt] = f2bf(w3[(co * CH + ci) * 9 + tap]);
    }
    return;
  }

  // ---- csr part (block = angle) ----
  int a = b;
  double theta = (double)a * (M_PI / 100.0);
  double irho  = 142.0 / 99.0;   // (floor(sqrt(2*100^2))+1)/(numRho-1)
  double ct = cos(theta) / irho;
  double st = sin(theta) / irho;

  if (t < 100) {
    for (int q = 0; q < 50; ++q) ((unsigned int*)&rowcnt[t][0])[q] = 0;
    int base = t * 100;
    for (int j = 0; j < 100; ++j) {
      double s = (double)(j - 50) * ct + (double)(t - 50) * st;
      int r = (int)rint(s) + 50;
      r = r < 0 ? 0 : (r > 99 ? 99 : r);
      sidx[base + j] = (unsigned char)r;
      rowcnt[t][r]++;
    }
  }
  if (t < 17) wstart[t] = NR;
  __syncthreads();

  if (t < 100) {
    int running = 0;
    for (int cc = 0; cc < 100; ++cc) {
      int tmp = rowcnt[cc][t];
      rowcnt[cc][t] = (unsigned short)running;
      running += tmp;
    }
    off[t + 1] = running;
  }
  __syncthreads();

  if (t == 0) {
    off[0] = 0;
    for (int bb = 0; bb < NR; ++bb) {
      int cb = off[bb + 1];
      off[bb + 1] = off[bb] + cb;
    }
  }
  __syncthreads();
  if (t <= NR) coff[a * (NR + 1) + t] = off[t];

  if (t < NR) {
    int o0 = off[t], o1 = off[t + 1];
    int ow = (o0 + ((o1 - o0) >> 1)) * 16 / HW;
    ow = ow > 15 ? 15 : ow;
    atomicMin(&wstart[ow], t);
  }
  __syncthreads();
  if (t == 0) {
    wstart[16] = NR;
    for (int ww = 15; ww >= 0; --ww)
      if (wstart[ww] == NR) wstart[ww] = wstart[ww + 1];
  }
  __syncthreads();
  if (t < 17) woff[a * 20 + t] = wstart[t];

  if (t < 100) {
    u16* dst = list + (size_t)a * HW;
    int base = t * 100;
    for (int j = 0; j < 100; ++j) {
      int r = sidx[base + j];
      int pos = off[r] + rowcnt[t][r];
      rowcnt[t][r]++;
      dst[pos] = (u16)(base + j);
    }
  }
}

// ---------------------------------------------------------------------------
// conv1 v3 (operand-swapped, plain loads — R16 state): M=co, N=hw, K=cin.
// ---------------------------------------------------------------------------
__global__ void __launch_bounds__(512)
k_conv1(const float* __restrict__ x, const u16* __restrict__ wbf1,
        const float* __restrict__ bias1, u16* __restrict__ h1t) {
  __shared__ char lds[32768];
  int n   = blockIdx.y;
  int hw0 = blockIdx.x * 128;
  int t   = threadIdx.x;
  int l   = t & 63, w = t >> 6, wm = w >> 2, wn = w & 3;

  const float* xn = x + (size_t)n * CIN * HW;
  int hwb  = hw0 + wn * 32 + (l & 15);
  int cinb = (l >> 4) * 8;

  f32x4 acc[4][2];
  f32x4 zf = {0.f, 0.f, 0.f, 0.f};
#pragma unroll
  for (int i = 0; i < 4; ++i)
#pragma unroll
    for (int j = 0; j < 2; ++j) acc[i][j] = zf;

  for (int kc = 0; kc < 8; ++kc) {
    short8 afr[4];
#pragma unroll
    for (int fm = 0; fm < 4; ++fm)
      afr[fm] = *(const short8*)(wbf1 + (((size_t)kc * 8 + wm * 4 + fm) * 64 + l) * 8);
    short8 bfr[2];
#pragma unroll
    for (int fn = 0; fn < 2; ++fn) {
      int hw = hwb + fn * 16;
      const float* col = xn + (size_t)(kc * 32 + cinb) * HW + hw;
      u16 vals[8];
      if (hw < HW) {
#pragma unroll
        for (int j = 0; j < 8; ++j) vals[j] = f2bf(col[(size_t)j * HW]);
      } else {
#pragma unroll
        for (int j = 0; j < 8; ++j) vals[j] = 0;
      }
      bfr[fn] = *(const short8*)vals;
    }
#pragma unroll
    for (int fm = 0; fm < 4; ++fm)
#pragma unroll
      for (int fn = 0; fn < 2; ++fn)
        acc[fm][fn] = __builtin_amdgcn_mfma_f32_16x16x32_bf16(afr[fm], bfr[fn], acc[fm][fn], 0, 0, 0);
  }

  float bi[4][4];
#pragma unroll
  for (int fm = 0; fm < 4; ++fm)
#pragma unroll
    for (int q = 0; q < 4; ++q)
      bi[fm][q] = bias1[wm * 64 + fm * 16 + (l >> 4) * 4 + q];

#pragma unroll
  for (int fm = 0; fm < 4; ++fm)
#pragma unroll
    for (int fn = 0; fn < 2; ++fn) {
      int mrow = wn * 32 + fn * 16 + (l & 15);
#pragma unroll
      for (int q = 0; q < 4; ++q) {
        int co = wm * 64 + fm * 16 + (l >> 4) * 4 + q;
        float y = fmaxf(acc[fm][fn][q] + bi[fm][q], 0.f);
        *(u16*)(lds + mrow * 256 + ((co * 2) ^ ((mrow & 15) << 4))) = f2bf(y);
      }
    }
  __syncthreads();
#pragma unroll
  for (int p = 0; p < 4; ++p) {
    int e = p * 512 + t;
    int m = e >> 4;
    int hw = hw0 + m;
    if (hw < HW) {
      uint4 v = *(const uint4*)(lds + m * 256 + (((e & 15) * 16) ^ ((m & 15) << 4)));
      *(uint4*)(h1t + ((size_t)n * HW + hw) * CH + (e & 15) * 8) = v;
    }
  }
}

// ---------------------------------------------------------------------------
// dht v8 (R16 state): per-wave bin ranges, scalar bookkeeping, packed acc.
// ---------------------------------------------------------------------------
__global__ void __launch_bounds__(256)
k_dht(const u16* __restrict__ h1t, const u16* __restrict__ list,
      const int* __restrict__ coff, const int* __restrict__ woff,
      u16* __restrict__ dht) {
  int id  = blockIdx.x;            // 0..6399
  int x   = id & 7;                // XCD
  int rem = id >> 3;               // 0..799
  int hi  = rem >= 400;
  int n   = (x << 1) | hi;
  int aq  = hi ? rem - 400 : rem;  // 0..399
  int a   = aq >> 2;
  int q   = aq & 3;
  int t   = threadIdx.x;
  int c   = t & 63;
  int w   = (t >> 6) + q * 4;

  const char* nimg = (const char*)h1t + (size_t)n * HW * 256;
  const int  c4    = c * 4;
  const u16* lst   = list + (size_t)a * HW;
  const int* cof   = coff + a * (NR + 1);
  const int* wof   = woff + a * 20;
  unsigned int* out32 = (unsigned int*)(dht + ((size_t)(n * NA + a) * NR) * CH) + c;

  int rlo = __builtin_amdgcn_readfirstlane(wof[w]);
  int rhi = __builtin_amdgcn_readfirstlane(wof[w + 1]);
  if (rlo >= rhi) return;

  int o0 = __builtin_amdgcn_readfirstlane(cof[rlo]);
  for (int r = rlo; r < rhi; ++r) {
    int o1 = __builtin_amdgcn_readfirstlane(cof[r + 1]);

    f32x2 A0 = {0.f, 0.f}, A1 = {0.f, 0.f};
    int k = o0;

    if (k & 1) {
      int p = __builtin_amdgcn_readfirstlane((int)lst[k]);
      unsigned int v = *(const unsigned int*)((nimg + ((size_t)p << 8)) + c4);
      A0 += bfpair(v);
      ++k;
    }

    for (; k + 16 <= o1; k += 16) {
      unsigned int ids[8];
#pragma unroll
      for (int j = 0; j < 8; ++j)
        ids[j] = __builtin_amdgcn_readfirstlane(*(const unsigned int*)(lst + k + 2 * j));
      unsigned int v[16];
#pragma unroll
      for (int j = 0; j < 8; ++j) {
        int p0 = (int)(ids[j] & 0xffffu);
        int p1 = (int)(ids[j] >> 16);
        v[2 * j]     = *(const unsigned int*)((nimg + ((size_t)p0 << 8)) + c4);
        v[2 * j + 1] = *(const unsigned int*)((nimg + ((size_t)p1 << 8)) + c4);
      }
#pragma unroll
      for (int j = 0; j < 16; ++j) {
        if (j & 1) A1 += bfpair(v[j]);
        else       A0 += bfpair(v[j]);
      }
    }
    for (; k + 2 <= o1; k += 2) {
      unsigned int ids = __builtin_amdgcn_readfirstlane(*(const unsigned int*)(lst + k));
      int p0 = (int)(ids & 0xffffu);
      int p1 = (int)(ids >> 16);
      unsigned int v0 = *(const unsigned int*)((nimg + ((size_t)p0 << 8)) + c4);
      unsigned int v1 = *(const unsigned int*)((nimg + ((size_t)p1 << 8)) + c4);
      A0 += bfpair(v0);
      A1 += bfpair(v1);
    }
    if (k < o1) {
      int p = __builtin_amdgcn_readfirstlane((int)lst[k]);
      unsigned int v = *(const unsigned int*)((nimg + ((size_t)p << 8)) + c4);
      A0 += bfpair(v);
    }

    float ax = A0.x + A1.x;
    float ay = A0.y + A1.y;
    unsigned int pk = (unsigned int)f2bf(ax) | ((unsigned int)f2bf(ay) << 16);
    out32[(size_t)r << 6] = pk;
    o0 = o1;
  }
}

// ---------------------------------------------------------------------------
// conv3x3 (MFMA implicit GEMM, 8 waves, 16x16 frags) — R16 state, plain stores.
// ---------------------------------------------------------------------------
template <int OUT_MODE>
__global__ void __launch_bounds__(512)
k_conv3x3(const u16* __restrict__ X, const u16* __restrict__ wbf,
          const float* __restrict__ pb, const float* __restrict__ pg,
          const float* __restrict__ pbe, void* __restrict__ out) {
  __shared__ uint4 lds4[2880];               // 46080 B
  char* lds = (char*)lds4;
  int n    = blockIdx.y;
  int tile = blockIdx.x;
  int ta = tile / 13, tr = tile - ta * 13;
  int a0 = ta * 16, r0 = tr * 8;
  int t  = threadIdx.x;
  int l  = t & 63, w = t >> 6, wm = w >> 2, wn = w & 3;

  {
    int sr32 = t >> 4;
    int cb   = (t & 15) * 16;
#pragma unroll
    for (int p = 0; p < 6; ++p) {
      int s = p * 32 + sr32;
      if (s < 180) {
        int sa = a0 - 1 + s / 10;
        int sr = r0 - 1 + s % 10;
        uint4 v = make_uint4(0, 0, 0, 0);
        if (sa >= 0 && sa < NA && sr >= 0 && sr < NR)
          v = *(const uint4*)(X + ((size_t)(n * NA + sa) * NR + sr) * CH + (t & 15) * 8);
        *(uint4*)(lds + s * 256 + (cb ^ ((s & 15) << 4))) = v;
      }
    }
  }
  __syncthreads();

  int sbase[4];
#pragma unroll
  for (int fm = 0; fm < 4; ++fm) {
    int m = wm * 64 + fm * 16 + (l & 15);
    sbase[fm] = ((m >> 3) + 1) * 10 + (m & 7) + 1;
  }
  int kseg = (l >> 4) * 16;

  f32x4 acc[4][2];
  f32x4 zf = {0.f, 0.f, 0.f, 0.f};
#pragma unroll
  for (int i = 0; i < 4; ++i)
#pragma unroll
    for (int j = 0; j < 2; ++j) acc[i][j] = zf;

  for (int tap = 0; tap < 9; ++tap) {
    int soff = (tap / 3 - 1) * 10 + (tap % 3 - 1);
#pragma unroll
    for (int kc = 0; kc < 4; ++kc) {
      short8 afr[4], bfr[2];
#pragma unroll
      for (int fm = 0; fm < 4; ++fm) {
        int s = sbase[fm] + soff;
        afr[fm] = *(const short8*)(lds + s * 256 + ((kc * 64 + kseg) ^ ((s & 15) << 4)));
      }
#pragma unroll
      for (int fn = 0; fn < 2; ++fn)
        bfr[fn] = *(const short8*)(wbf + (((size_t)(tap * 4 + kc) * 8 + wn * 2 + fn) * 64 + l) * 8);
#pragma unroll
      for (int fm = 0; fm < 4; ++fm)
#pragma unroll
        for (int fn = 0; fn < 2; ++fn)
          acc[fm][fn] = __builtin_amdgcn_mfma_f32_16x16x32_bf16(afr[fm], bfr[fn], acc[fm][fn], 0, 0, 0);
    }
  }

  float sc[2], sh[2];
#pragma unroll
  for (int fn = 0; fn < 2; ++fn) {
    int co = wn * 32 + fn * 16 + (l & 15);
    float s = pg[co] / sqrtf(1.f + 1e-5f);
    sc[fn] = s;
    sh[fn] = pb[co] * s + pbe[co];
  }

  if (OUT_MODE == 0) {
    __syncthreads();
#pragma unroll
    for (int fm = 0; fm < 4; ++fm)
#pragma unroll
      for (int fn = 0; fn < 2; ++fn) {
        int co = wn * 32 + fn * 16 + (l & 15);
#pragma unroll
        for (int q = 0; q < 4; ++q) {
          int m = wm * 64 + fm * 16 + (l >> 4) * 4 + q;
          float y = fmaxf(acc[fm][fn][q] * sc[fn] + sh[fn], 0.f);
          *(u16*)(lds + m * 256 + ((co * 2) ^ ((m & 15) << 4))) = f2bf(y);
        }
      }
    __syncthreads();
    u16* o = (u16*)out;
#pragma unroll
    for (int p = 0; p < 4; ++p) {
      int e = p * 512 + t;
      int m = e >> 4;
      int a = a0 + (m >> 3), r = r0 + (m & 7);
      if (a < NA && r < NR) {
        uint4 v = *(const uint4*)(lds + m * 256 + (((e & 15) * 16) ^ ((m & 15) << 4)));
        *(uint4*)(o + ((size_t)(n * NA + a) * NR + r) * CH + (e & 15) * 8) = v;
      }
    }
  } else {
    float* o = (float*)out;
#pragma unroll
    for (int fm = 0; fm < 4; ++fm) {
      int mb = wm * 64 + fm * 16 + (l >> 4) * 4;
      int a  = a0 + (mb >> 3), rr = r0 + (mb & 7);
      if (a < NA && rr < NR) {
#pragma unroll
        for (int fn = 0; fn < 2; ++fn) {
          int co = wn * 32 + fn * 16 + (l & 15);
          float4 v;
          v.x = fmaxf(acc[fm][fn][0] * sc[fn] + sh[fn], 0.f);
          v.y = fmaxf(acc[fm][fn][1] * sc[fn] + sh[fn], 0.f);
          v.z = fmaxf(acc[fm][fn][2] * sc[fn] + sh[fn], 0.f);
          v.w = fmaxf(acc[fm][fn][3] * sc[fn] + sh[fn], 0.f);
          *(float4*)(o + ((size_t)n * CH + co) * HW + a * NR + rr) = v;
        }
      }
    }
  }
}

// ---------------------------------------------------------------------------
extern "C" void kernel_launch(void* const* d_in, const int* in_sizes, int n_in,
                              void* d_out, int out_size, void* d_ws, size_t ws_size,
                              hipStream_t stream) {
  if (n_in < 13) return;
  const float* x   = (const float*)d_in[0];
  const float* w1  = (const float*)d_in[1];
  const float* b1  = (const float*)d_in[2];
  const float* g1  = (const float*)d_in[3];
  const float* be1 = (const float*)d_in[4];
  const float* w2  = (const float*)d_in[5];
  const float* b2  = (const float*)d_in[6];
  const float* g2  = (const float*)d_in[7];
  const float* be2 = (const float*)d_in[8];
  const float* w3  = (const float*)d_in[9];
  const float* b3  = (const float*)d_in[10];
  const float* g3  = (const float*)d_in[11];
  const float* be3 = (const float*)d_in[12];

  // workspace layout (256B-aligned)
  const size_t o_list  = 0;                    // u16[100][10000]     = 2,000,000
  const size_t o_coff  = 2000128;              // int[100][101]       =    40,400
  const size_t o_woff  = 2040576;              // int[100][20]        =     8,000
  const size_t o_wbf1  = 2048768;              // u16[32768]          =    65,536
  const size_t o_wbf2  = o_wbf1 + 65536;       // u16[147456]         =   294,912
  const size_t o_wbf3  = o_wbf2 + 294912;      // u16[147456]         =   294,912
  const size_t o_bias1 = o_wbf3 + 294912;      // f32[128]            =       512 (pad 1024)
  const size_t o_dht   = o_bias1 + 1024;       // 40,960,000
  const size_t o_c2    = o_dht + 40960000;     // 40,960,000
  const size_t need    = o_c2 + 40960000;      // ~84.6 MB
  if (ws_size < need) return;

  char*  ws    = (char*)d_ws;
  u16*   list  = (u16*)(ws + o_list);
  int*   coff  = (int*)(ws + o_coff);
  int*   woff  = (int*)(ws + o_woff);
  u16*   wbf1  = (u16*)(ws + o_wbf1);
  u16*   wbf2  = (u16*)(ws + o_wbf2);
  u16*   wbf3  = (u16*)(ws + o_wbf3);
  float* bias1 = (float*)(ws + o_bias1);
  u16*   dht   = (u16*)(ws + o_dht);
  u16*   c2    = (u16*)(ws + o_c2);
  u16*   h1t   = (u16*)d_out;   // bf16 scratch inside f32 out (dead before conv3)

  k_prep_csr<<<dim3(676), dim3(256), 0, stream>>>(w1, w2, w3, g1, b1, be1,
                                                  wbf1, wbf2, wbf3, bias1,
                                                  list, coff, woff);
  k_conv1<<<dim3(79, 16), dim3(512), 0, stream>>>(x, wbf1, bias1, h1t);
  k_dht<<<dim3(6400), dim3(256), 0, stream>>>(h1t, list, coff, woff, dht);
  k_conv3x3<0><<<dim3(91, 16), dim3(512), 0, stream>>>(dht, wbf2, b2, g2, be2, (void*)c2);
  k_conv3x3<1><<<dim3(91, 16), dim3(512), 0, stream>>>(c2, wbf3, b3, g3, be3, d_out);
}